// Round 5
// baseline (4585.464 us; speedup 1.0000x reference)
//
#include <hip/hip_runtime.h>
#include <hip/hip_bf16.h>

#define N_NODES 100000
#define N_EDGES 1600000
#define N_FEAT 128
#define HID 64
#define N_GRAPHS 64
#define N_OUT 10

// ---------- index dtype probe: 1 = int64 storage, 0 = int32 storage ----------
__global__ void k_detect(const int* raw, int* flag) {
    __shared__ int any;
    if (threadIdx.x == 0) any = 0;
    __syncthreads();
    int v = raw[2 * threadIdx.x + 1] | raw[2 * (threadIdx.x + 256) + 1] |
            raw[2 * (threadIdx.x + 512) + 1] | raw[2 * (threadIdx.x + 768) + 1];
    if (v != 0) any = 1;  // benign race
    __syncthreads();
    if (threadIdx.x == 0) *flag = (any == 0) ? 1 : 0;
}

// ---------- narrow int64->int32 (or plain copy) ----------
__global__ void k_cvt(const int* raw, const int* flag, int* out, int n) {
    int i = blockIdx.x * 256 + threadIdx.x;
    if (i < n) out[i] = (*flag) ? raw[2 * (size_t)i] : raw[i];
}

// ---------- degree / normalization ----------
__global__ void k_init_deg(float* deg) {
    int i = blockIdx.x * 256 + threadIdx.x;
    if (i < N_NODES) deg[i] = 1.0f;  // self loop
}

__global__ void k_deg_scatter(const int* col, float* deg) {
    int e = blockIdx.x * 256 + threadIdx.x;
    if (e < N_EDGES) {
        unsigned c = (unsigned)col[e];
        if (c < N_NODES) atomicAdd(&deg[c], 1.0f);
    }
}

__global__ void k_rsqrt(float* deg) {
    int i = blockIdx.x * 256 + threadIdx.x;
    if (i < N_NODES) deg[i] = rsqrtf(deg[i]);
}

// ---------- projection: g[i,:] = dis[i] * (h[i,:] @ W)  ----------
template <int K>
__global__ __launch_bounds__(256) void k_proj(const float* in, const float* W,
                                              const float* dis, float* g) {
    __shared__ float Wl[K * 64];
    __shared__ float rowbuf[4][K];
    for (int idx = threadIdx.x; idx < K * 64; idx += 256) Wl[idx] = W[idx];
    int wave = threadIdx.x >> 6;
    int lane = threadIdx.x & 63;
    int row = blockIdx.x * 4 + wave;
    if (row < N_NODES) {
        for (int k = lane; k < K; k += 64) rowbuf[wave][k] = in[(size_t)row * K + k];
    }
    __syncthreads();
    if (row < N_NODES) {
        float acc = 0.f;
#pragma unroll 8
        for (int k = 0; k < K; k++) acc = fmaf(rowbuf[wave][k], Wl[k * 64 + lane], acc);
        g[(size_t)row * 64 + lane] = dis[row] * acc;
    }
}

// ---------- edge scatter: acc[c,:] += g[r,:] (16 lanes/edge, float4) ----------
__global__ __launch_bounds__(256) void k_scatter(const int* row, const int* col,
                                                 const float* g, float* acc) {
    long long tid = (long long)blockIdx.x * 256 + threadIdx.x;
    int e = (int)(tid >> 4);
    int q = (int)(tid & 15);
    if (e < N_EDGES) {
        unsigned r = (unsigned)row[e], c = (unsigned)col[e];
        if (r < N_NODES && c < N_NODES) {
            const float4 v = *(const float4*)(g + (size_t)r * 64 + q * 4);
            float* dst = acc + (size_t)c * 64 + q * 4;
            atomicAdd(dst + 0, v.x);
            atomicAdd(dst + 1, v.y);
            atomicAdd(dst + 2, v.z);
            atomicAdd(dst + 3, v.w);
        }
    }
}

// ---------- finalize: h = act(dis*(acc+g) + b) in-place into acc ----------
template <bool RELU>
__global__ void k_finalize(float* acc, const float* g, const float* dis, const float* b) {
    int i = blockIdx.x * 256 + threadIdx.x;
    if (i < N_NODES * 64) {
        int node = i >> 6, j = i & 63;
        float v = dis[node] * (acc[i] + g[i]) + b[j];
        if (RELU) v = fmaxf(v, 0.f);
        acc[i] = v;
    }
}

// ---------- pooling (batch sorted): per-graph sums + counts ----------
__global__ void k_pool(const float* h, const int* batch, float* sums, float* cnts) {
    const int R = 128;
    int wave = (blockIdx.x * 256 + threadIdx.x) >> 6;
    int lane = threadIdx.x & 63;
    int base = wave * R;
    if (base >= N_NODES) return;
    int end = min(base + R, N_NODES);
    float acc = 0.f;
    int cur = batch[base];
    int cnt = 0;
    for (int r = base; r < end; r++) {
        int b = batch[r];
        if (b != cur) {
            if ((unsigned)cur < N_GRAPHS) {
                atomicAdd(&sums[cur * 64 + lane], acc);
                if (lane == 0) atomicAdd(&cnts[cur], (float)cnt);
            }
            acc = 0.f;
            cnt = 0;
            cur = b;
        }
        acc += h[(size_t)r * 64 + lane];
        cnt++;
    }
    if ((unsigned)cur < N_GRAPHS) {
        atomicAdd(&sums[cur * 64 + lane], acc);
        if (lane == 0) atomicAdd(&cnts[cur], (float)cnt);
    }
}

// ---------- head: out[g,o] = (sums[g,:]/cnt[g]) @ Wlin + blin  (fp32 output!) ----------
__global__ void k_head(const float* sums, const float* cnts, const float* Wlin,
                       const float* blin, float* out) {
    int t = blockIdx.x * 64 + threadIdx.x;
    if (t < N_GRAPHS * N_OUT) {
        int gph = t / N_OUT, o = t % N_OUT;
        float c = fmaxf(cnts[gph], 1.0f);
        float a = 0.f;
        for (int j = 0; j < HID; j++) a += sums[gph * 64 + j] * Wlin[j * N_OUT + o];
        out[t] = a / c + blin[o];
    }
}

extern "C" void kernel_launch(void* const* d_in, const int* in_sizes, int n_in,
                              void* d_out, int out_size, void* d_ws, size_t ws_size,
                              hipStream_t stream) {
    // --- resolve inputs by SIZE (robust to any harness input ordering) ---
    const float *x = nullptr, *W1 = nullptr, *W2 = nullptr, *W3 = nullptr, *Wlin = nullptr;
    const float *b1 = nullptr, *b2 = nullptr, *b3 = nullptr, *blin = nullptr;
    const int *ei = nullptr, *bat = nullptr;
    int n4096 = 0, n64 = 0;
    for (int i = 0; i < n_in; i++) {
        switch (in_sizes[i]) {
            case N_NODES * N_FEAT:  x    = (const float*)d_in[i]; break;   // 12.8M
            case 2 * N_EDGES:       ei   = (const int*)d_in[i];   break;   // 3.2M
            case N_NODES:           bat  = (const int*)d_in[i];   break;   // 100K
            case N_FEAT * HID:      W1   = (const float*)d_in[i]; break;   // 8192
            case HID * HID:                                                 // 4096 x2
                if (n4096++ == 0) W2 = (const float*)d_in[i];
                else              W3 = (const float*)d_in[i];
                break;
            case HID * N_OUT:       Wlin = (const float*)d_in[i]; break;   // 640
            case HID:                                                       // 64 x3 (all zeros)
                if (n64 == 0) b1 = (const float*)d_in[i];
                else if (n64 == 1) b2 = (const float*)d_in[i];
                else b3 = (const float*)d_in[i];
                n64++;
                break;
            case N_OUT:             blin = (const float*)d_in[i]; break;   // 10
            default: break;
        }
    }
    if (!x || !ei || !bat || !W1 || !W2 || !W3 || !Wlin || !b1 || !b2 || !b3 || !blin) {
        // fallback: setup_inputs() dict order
        x    = (const float*)d_in[0];
        ei   = (const int*)d_in[1];
        bat  = (const int*)d_in[2];
        W1   = (const float*)d_in[3];  b1   = (const float*)d_in[4];
        W2   = (const float*)d_in[5];  b2   = (const float*)d_in[6];
        W3   = (const float*)d_in[7];  b3   = (const float*)d_in[8];
        Wlin = (const float*)d_in[9];  blin = (const float*)d_in[10];
    }
    float* out = (float*)d_out;  // reference output dtype is float32

    char* ws = (char*)d_ws;
    size_t off = 0;
    float* A    = (float*)(ws + off); off += (size_t)N_NODES * 64 * 4;
    float* B    = (float*)(ws + off); off += (size_t)N_NODES * 64 * 4;
    float* dis  = (float*)(ws + off); off += (size_t)N_NODES * 4;
    float* sums = (float*)(ws + off); off += (size_t)N_GRAPHS * HID * 4;
    float* cnts = (float*)(ws + off); off += (size_t)N_GRAPHS * 4;
    int*   idx  = (int*)(ws + off);   off += (size_t)2 * N_EDGES * 4;
    int*   bat32= (int*)(ws + off);   off += (size_t)N_NODES * 4;
    int*   flag = (int*)(ws + off);   off += 4;

    const int* row = idx;            // edge_index[0] = source
    const int* col = idx + N_EDGES;  // edge_index[1] = target

    const int nb_nodes = (N_NODES + 255) / 256;
    const int nb_proj  = (N_NODES + 3) / 4;
    const int nb_feat  = (N_NODES * 64 + 255) / 256;
    const int nb_scat  = (N_EDGES * 16 + 255) / 256;

    // --- index dtype detection + narrowing ---
    k_detect<<<1, 256, 0, stream>>>(ei, flag);
    k_cvt<<<(2 * N_EDGES + 255) / 256, 256, 0, stream>>>(ei, flag, idx, 2 * N_EDGES);
    k_cvt<<<nb_nodes, 256, 0, stream>>>(bat, flag, bat32, N_NODES);

    // --- normalization ---
    k_init_deg<<<nb_nodes, 256, 0, stream>>>(dis);
    k_deg_scatter<<<(N_EDGES + 255) / 256, 256, 0, stream>>>(col, dis);
    k_rsqrt<<<nb_nodes, 256, 0, stream>>>(dis);

    // conv1: x(fp32,128) -> A
    k_proj<128><<<nb_proj, 256, 0, stream>>>(x, W1, dis, B);
    hipMemsetAsync(A, 0, (size_t)N_NODES * 64 * 4, stream);
    k_scatter<<<nb_scat, 256, 0, stream>>>(row, col, B, A);
    k_finalize<true><<<nb_feat, 256, 0, stream>>>(A, B, dis, b1);

    // conv2: A(fp32,64) -> A
    k_proj<64><<<nb_proj, 256, 0, stream>>>(A, W2, dis, B);
    hipMemsetAsync(A, 0, (size_t)N_NODES * 64 * 4, stream);
    k_scatter<<<nb_scat, 256, 0, stream>>>(row, col, B, A);
    k_finalize<true><<<nb_feat, 256, 0, stream>>>(A, B, dis, b2);

    // conv3: A(fp32,64) -> A (no relu)
    k_proj<64><<<nb_proj, 256, 0, stream>>>(A, W3, dis, B);
    hipMemsetAsync(A, 0, (size_t)N_NODES * 64 * 4, stream);
    k_scatter<<<nb_scat, 256, 0, stream>>>(row, col, B, A);
    k_finalize<false><<<nb_feat, 256, 0, stream>>>(A, B, dis, b3);

    // pool + head
    hipMemsetAsync(sums, 0, (size_t)(N_GRAPHS * HID + N_GRAPHS) * 4, stream);
    const int nwaves = (N_NODES + 127) / 128;
    k_pool<<<(nwaves * 64 + 255) / 256, 256, 0, stream>>>(A, bat32, sums, cnts);
    k_head<<<(N_GRAPHS * N_OUT + 63) / 64, 64, 0, stream>>>(sums, cnts, Wlin, blin, out);
}

// Round 6
// 842.602 us; speedup vs baseline: 5.4420x; 5.4420x over previous
//
#include <hip/hip_runtime.h>
#include <hip/hip_bf16.h>

#define N_NODES 100000
#define N_EDGES 1600000
#define N_FEAT 128
#define HID 64
#define N_GRAPHS 64
#define N_OUT 10
#define SCAN_B 1024
#define NBLK ((N_NODES + SCAN_B - 1) / SCAN_B)  // 98

// ---------- index dtype probe: 1 = int64 storage, 0 = int32 storage ----------
__global__ void k_detect(const int* raw, int* flag) {
    __shared__ int any;
    if (threadIdx.x == 0) any = 0;
    __syncthreads();
    int v = raw[2 * threadIdx.x + 1] | raw[2 * (threadIdx.x + 256) + 1] |
            raw[2 * (threadIdx.x + 512) + 1] | raw[2 * (threadIdx.x + 768) + 1];
    if (v != 0) any = 1;  // benign race
    __syncthreads();
    if (threadIdx.x == 0) *flag = (any == 0) ? 1 : 0;
}

__device__ __forceinline__ int ldidx(const int* raw, int f, size_t i) {
    return f ? raw[2 * i] : raw[i];
}

// ---------- in-degree (edges into col) ----------
__global__ void k_deg(const int* ei, const int* flag, int* indeg) {
    int e = blockIdx.x * 256 + threadIdx.x;
    if (e < N_EDGES) {
        int f = *flag;
        unsigned c = (unsigned)ldidx(ei, f, (size_t)N_EDGES + e);
        if (c < N_NODES) atomicAdd(&indeg[c], 1);
    }
}

__global__ void k_dis(const int* indeg, float* dis) {
    int i = blockIdx.x * 256 + threadIdx.x;
    if (i < N_NODES) dis[i] = rsqrtf((float)indeg[i] + 1.0f);
}

// ---------- 3-kernel exclusive prefix scan of indeg -> offs ----------
__global__ __launch_bounds__(SCAN_B) void k_scan1(const int* indeg, int* incl, int* bsum) {
    __shared__ int tmp[SCAN_B];
    int i = blockIdx.x * SCAN_B + threadIdx.x;
    tmp[threadIdx.x] = (i < N_NODES) ? indeg[i] : 0;
    __syncthreads();
    for (int d = 1; d < SCAN_B; d <<= 1) {
        int t = (threadIdx.x >= d) ? tmp[threadIdx.x - d] : 0;
        __syncthreads();
        tmp[threadIdx.x] += t;
        __syncthreads();
    }
    if (i < N_NODES) incl[i] = tmp[threadIdx.x];
    if (threadIdx.x == SCAN_B - 1) bsum[blockIdx.x] = tmp[threadIdx.x];
}

__global__ void k_scan2(int* bsum) {
    __shared__ int tmp[128];
    tmp[threadIdx.x] = (threadIdx.x < NBLK) ? bsum[threadIdx.x] : 0;
    __syncthreads();
    for (int d = 1; d < 128; d <<= 1) {
        int t = (threadIdx.x >= d) ? tmp[threadIdx.x - d] : 0;
        __syncthreads();
        tmp[threadIdx.x] += t;
        __syncthreads();
    }
    if (threadIdx.x < NBLK) bsum[threadIdx.x] = tmp[threadIdx.x];
}

__global__ __launch_bounds__(SCAN_B) void k_scan3(const int* indeg, const int* incl,
                                                  const int* bsum, int* offs, int* fill) {
    int i = blockIdx.x * SCAN_B + threadIdx.x;
    if (i < N_NODES) {
        int pre = (blockIdx.x > 0) ? bsum[blockIdx.x - 1] : 0;
        offs[i] = incl[i] - indeg[i] + pre;
        fill[i] = 0;
    }
}

// ---------- CSR placement: srcs grouped by destination ----------
__global__ void k_place(const int* ei, const int* flag, const int* offs, int* fill, int* srcs) {
    int e = blockIdx.x * 256 + threadIdx.x;
    if (e < N_EDGES) {
        int f = *flag;
        unsigned r = (unsigned)ldidx(ei, f, (size_t)e);
        unsigned c = (unsigned)ldidx(ei, f, (size_t)N_EDGES + e);
        if (r < N_NODES && c < N_NODES) {
            int p = offs[c] + atomicAdd(&fill[c], 1);
            srcs[p] = (int)r;
        }
    }
}

// ---------- projection: g[i,:] = dis[i] * (h[i,:] @ W)  ----------
template <int K>
__global__ __launch_bounds__(256) void k_proj(const float* in, const float* W,
                                              const float* dis, float* g) {
    __shared__ float Wl[K * 64];
    __shared__ float rowbuf[4][K];
    for (int idx = threadIdx.x; idx < K * 64; idx += 256) Wl[idx] = W[idx];
    int wave = threadIdx.x >> 6;
    int lane = threadIdx.x & 63;
    int row = blockIdx.x * 4 + wave;
    if (row < N_NODES) {
        for (int k = lane; k < K; k += 64) rowbuf[wave][k] = in[(size_t)row * K + k];
    }
    __syncthreads();
    if (row < N_NODES) {
        float acc = 0.f;
#pragma unroll 8
        for (int k = 0; k < K; k++) acc = fmaf(rowbuf[wave][k], Wl[k * 64 + lane], acc);
        g[(size_t)row * 64 + lane] = dis[row] * acc;
    }
}

// ---------- CSR aggregation + finalize: out[c,:] = act(dis[c]*(g[c,:] + sum g[src,:]) + b) ----------
template <bool RELU>
__global__ __launch_bounds__(256) void k_agg(const float* g, const int* srcs, const int* offs,
                                             const int* indeg, const float* dis, const float* b,
                                             float* out) {
    int node = (blockIdx.x * 256 + threadIdx.x) >> 6;
    int lane = threadIdx.x & 63;
    if (node >= N_NODES) return;
    int beg = offs[node];
    int deg = indeg[node];
    float acc = g[(size_t)node * 64 + lane];  // self loop
    int done = 0;
    while (done < deg) {
        int rem = deg - done;
        int cnt = rem < 64 ? rem : 64;
        int sv = (lane < cnt) ? srcs[beg + done + lane] : 0;
        for (int j = 0; j < cnt; j++) {
            int s = __shfl(sv, j);
            acc += g[(size_t)s * 64 + lane];
        }
        done += cnt;
    }
    float v = dis[node] * acc + b[lane];
    if (RELU) v = fmaxf(v, 0.f);
    out[(size_t)node * 64 + lane] = v;
}

// ---------- pooling (batch sorted): per-graph sums + counts ----------
__global__ void k_pool(const float* h, const int* bat, const int* flag, float* sums, float* cnts) {
    const int R = 128;
    int wave = (blockIdx.x * 256 + threadIdx.x) >> 6;
    int lane = threadIdx.x & 63;
    int base = wave * R;
    if (base >= N_NODES) return;
    int f = *flag;
    int end = min(base + R, N_NODES);
    float acc = 0.f;
    int cur = ldidx(bat, f, (size_t)base);
    int cnt = 0;
    for (int r = base; r < end; r++) {
        int b = ldidx(bat, f, (size_t)r);
        if (b != cur) {
            if ((unsigned)cur < N_GRAPHS) {
                atomicAdd(&sums[cur * 64 + lane], acc);
                if (lane == 0) atomicAdd(&cnts[cur], (float)cnt);
            }
            acc = 0.f;
            cnt = 0;
            cur = b;
        }
        acc += h[(size_t)r * 64 + lane];
        cnt++;
    }
    if ((unsigned)cur < N_GRAPHS) {
        atomicAdd(&sums[cur * 64 + lane], acc);
        if (lane == 0) atomicAdd(&cnts[cur], (float)cnt);
    }
}

// ---------- head: out[g,o] = (sums[g,:]/cnt[g]) @ Wlin + blin (fp32 out) ----------
__global__ void k_head(const float* sums, const float* cnts, const float* Wlin,
                       const float* blin, float* out) {
    int t = blockIdx.x * 64 + threadIdx.x;
    if (t < N_GRAPHS * N_OUT) {
        int gph = t / N_OUT, o = t % N_OUT;
        float c = fmaxf(cnts[gph], 1.0f);
        float a = 0.f;
        for (int j = 0; j < HID; j++) a += sums[gph * 64 + j] * Wlin[j * N_OUT + o];
        out[t] = a / c + blin[o];
    }
}

extern "C" void kernel_launch(void* const* d_in, const int* in_sizes, int n_in,
                              void* d_out, int out_size, void* d_ws, size_t ws_size,
                              hipStream_t stream) {
    // --- resolve inputs by SIZE (robust to any harness input ordering) ---
    const float *x = nullptr, *W1 = nullptr, *W2 = nullptr, *W3 = nullptr, *Wlin = nullptr;
    const float *b1 = nullptr, *b2 = nullptr, *b3 = nullptr, *blin = nullptr;
    const int *ei = nullptr, *bat = nullptr;
    int n4096 = 0, n64 = 0;
    for (int i = 0; i < n_in; i++) {
        switch (in_sizes[i]) {
            case N_NODES * N_FEAT:  x    = (const float*)d_in[i]; break;
            case 2 * N_EDGES:       ei   = (const int*)d_in[i];   break;
            case N_NODES:           bat  = (const int*)d_in[i];   break;
            case N_FEAT * HID:      W1   = (const float*)d_in[i]; break;
            case HID * HID:
                if (n4096++ == 0) W2 = (const float*)d_in[i];
                else              W3 = (const float*)d_in[i];
                break;
            case HID * N_OUT:       Wlin = (const float*)d_in[i]; break;
            case HID:
                if (n64 == 0) b1 = (const float*)d_in[i];
                else if (n64 == 1) b2 = (const float*)d_in[i];
                else b3 = (const float*)d_in[i];
                n64++;
                break;
            case N_OUT:             blin = (const float*)d_in[i]; break;
            default: break;
        }
    }
    if (!x || !ei || !bat || !W1 || !W2 || !W3 || !Wlin || !b1 || !b2 || !b3 || !blin) {
        x    = (const float*)d_in[0];
        ei   = (const int*)d_in[1];
        bat  = (const int*)d_in[2];
        W1   = (const float*)d_in[3];  b1   = (const float*)d_in[4];
        W2   = (const float*)d_in[5];  b2   = (const float*)d_in[6];
        W3   = (const float*)d_in[7];  b3   = (const float*)d_in[8];
        Wlin = (const float*)d_in[9];  blin = (const float*)d_in[10];
    }
    float* out = (float*)d_out;  // fp32 output

    char* ws = (char*)d_ws;
    size_t off = 0;
    float* A     = (float*)(ws + off); off += (size_t)N_NODES * 64 * 4;
    float* B     = (float*)(ws + off); off += (size_t)N_NODES * 64 * 4;
    float* dis   = (float*)(ws + off); off += (size_t)N_NODES * 4;
    float* sums  = (float*)(ws + off); off += (size_t)N_GRAPHS * HID * 4;
    float* cnts  = (float*)(ws + off); off += (size_t)N_GRAPHS * 4;
    int*   indeg = (int*)(ws + off);   off += (size_t)N_NODES * 4;
    int*   incl  = (int*)(ws + off);   off += (size_t)N_NODES * 4;
    int*   offs  = (int*)(ws + off);   off += (size_t)N_NODES * 4;
    int*   fill  = (int*)(ws + off);   off += (size_t)N_NODES * 4;
    int*   bsum  = (int*)(ws + off);   off += 128 * 4;
    int*   srcs  = (int*)(ws + off);   off += (size_t)N_EDGES * 4;
    int*   flag  = (int*)(ws + off);   off += 4;

    const int nb_nodes = (N_NODES + 255) / 256;
    const int nb_edges = (N_EDGES + 255) / 256;
    const int nb_proj  = (N_NODES + 3) / 4;
    const int nb_agg   = (N_NODES * 64 + 255) / 256;

    // --- index dtype detection ---
    k_detect<<<1, 256, 0, stream>>>(ei, flag);

    // --- CSR build (once, reused by all 3 convs) ---
    hipMemsetAsync(indeg, 0, (size_t)N_NODES * 4, stream);
    k_deg<<<nb_edges, 256, 0, stream>>>(ei, flag, indeg);
    k_dis<<<nb_nodes, 256, 0, stream>>>(indeg, dis);
    k_scan1<<<NBLK, SCAN_B, 0, stream>>>(indeg, incl, bsum);
    k_scan2<<<1, 128, 0, stream>>>(bsum);
    k_scan3<<<NBLK, SCAN_B, 0, stream>>>(indeg, incl, bsum, offs, fill);
    k_place<<<nb_edges, 256, 0, stream>>>(ei, flag, offs, fill, srcs);

    // conv1: x(fp32,128) -> B(g) -> A
    k_proj<128><<<nb_proj, 256, 0, stream>>>(x, W1, dis, B);
    k_agg<true><<<nb_agg, 256, 0, stream>>>(B, srcs, offs, indeg, dis, b1, A);

    // conv2: A -> B(g) -> A
    k_proj<64><<<nb_proj, 256, 0, stream>>>(A, W2, dis, B);
    k_agg<true><<<nb_agg, 256, 0, stream>>>(B, srcs, offs, indeg, dis, b2, A);

    // conv3: A -> B(g) -> A (no relu)
    k_proj<64><<<nb_proj, 256, 0, stream>>>(A, W3, dis, B);
    k_agg<false><<<nb_agg, 256, 0, stream>>>(B, srcs, offs, indeg, dis, b3, A);

    // pool + head
    hipMemsetAsync(sums, 0, (size_t)(N_GRAPHS * HID + N_GRAPHS) * 4, stream);
    const int nwaves = (N_NODES + 127) / 128;
    k_pool<<<(nwaves * 64 + 255) / 256, 256, 0, stream>>>(A, bat, flag, sums, cnts);
    k_head<<<(N_GRAPHS * N_OUT + 63) / 64, 64, 0, stream>>>(sums, cnts, Wlin, blin, out);
}

// Round 7
// 728.913 us; speedup vs baseline: 6.2908x; 1.1560x over previous
//
#include <hip/hip_runtime.h>
#include <hip/hip_bf16.h>

#define N_NODES 100000
#define N_EDGES 1600000
#define N_FEAT 128
#define HID 64
#define N_GRAPHS 64
#define N_OUT 10
#define SCAN_B 1024
#define NBLK ((N_NODES + SCAN_B - 1) / SCAN_B)  // 98
#define XRANGES 8
#define RANGE_SZ ((N_NODES + XRANGES - 1) / XRANGES)  // 12500
#define ECHUNKS ((N_EDGES + 255) / 256)  // 6250

// ---------- index dtype probe: 1 = int64 storage, 0 = int32 storage ----------
__global__ void k_detect(const int* raw, int* flag) {
    __shared__ int any;
    if (threadIdx.x == 0) any = 0;
    __syncthreads();
    int v = raw[2 * threadIdx.x + 1] | raw[2 * (threadIdx.x + 256) + 1] |
            raw[2 * (threadIdx.x + 512) + 1] | raw[2 * (threadIdx.x + 768) + 1];
    if (v != 0) any = 1;  // benign race
    __syncthreads();
    if (threadIdx.x == 0) *flag = (any == 0) ? 1 : 0;
}

__device__ __forceinline__ int ldidx(const int* raw, int f, size_t i) {
    return f ? raw[2 * i] : raw[i];
}

// ---------- in-degree, XCD-range filtered (block b handles col range b&7) ----------
__global__ void k_deg(const int* ei, const int* flag, int* indeg) {
    unsigned X = blockIdx.x & (XRANGES - 1);
    int e = (blockIdx.x >> 3) * 256 + threadIdx.x;
    if (e < N_EDGES) {
        int f = *flag;
        unsigned c = (unsigned)ldidx(ei, f, (size_t)N_EDGES + e);
        if (c < N_NODES && c / RANGE_SZ == X) atomicAdd(&indeg[c], 1);
    }
}

__global__ void k_dis(const int* indeg, float* dis) {
    int i = blockIdx.x * 256 + threadIdx.x;
    if (i < N_NODES) dis[i] = rsqrtf((float)indeg[i] + 1.0f);
}

// ---------- 3-kernel exclusive prefix scan of indeg -> offs ----------
__global__ __launch_bounds__(SCAN_B) void k_scan1(const int* indeg, int* incl, int* bsum) {
    __shared__ int tmp[SCAN_B];
    int i = blockIdx.x * SCAN_B + threadIdx.x;
    tmp[threadIdx.x] = (i < N_NODES) ? indeg[i] : 0;
    __syncthreads();
    for (int d = 1; d < SCAN_B; d <<= 1) {
        int t = (threadIdx.x >= d) ? tmp[threadIdx.x - d] : 0;
        __syncthreads();
        tmp[threadIdx.x] += t;
        __syncthreads();
    }
    if (i < N_NODES) incl[i] = tmp[threadIdx.x];
    if (threadIdx.x == SCAN_B - 1) bsum[blockIdx.x] = tmp[threadIdx.x];
}

__global__ void k_scan2(int* bsum) {
    __shared__ int tmp[128];
    tmp[threadIdx.x] = (threadIdx.x < NBLK) ? bsum[threadIdx.x] : 0;
    __syncthreads();
    for (int d = 1; d < 128; d <<= 1) {
        int t = (threadIdx.x >= d) ? tmp[threadIdx.x - d] : 0;
        __syncthreads();
        tmp[threadIdx.x] += t;
        __syncthreads();
    }
    if (threadIdx.x < NBLK) bsum[threadIdx.x] = tmp[threadIdx.x];
}

__global__ __launch_bounds__(SCAN_B) void k_scan3(const int* indeg, const int* incl,
                                                  const int* bsum, int* offs, int* fill) {
    int i = blockIdx.x * SCAN_B + threadIdx.x;
    if (i < N_NODES) {
        int pre = (blockIdx.x > 0) ? bsum[blockIdx.x - 1] : 0;
        offs[i] = incl[i] - indeg[i] + pre;
        fill[i] = 0;
    }
}

// ---------- CSR placement, XCD-range filtered ----------
// Block b processes edge chunk (b>>3), placing only cols in range (b&7).
// Keeps each srcs cache line dirty in ~one XCD's L2 -> writeback ~= payload.
__global__ void k_place(const int* ei, const int* flag, const int* offs, int* fill, int* srcs) {
    unsigned X = blockIdx.x & (XRANGES - 1);
    int e = (blockIdx.x >> 3) * 256 + threadIdx.x;
    if (e < N_EDGES) {
        int f = *flag;
        unsigned c = (unsigned)ldidx(ei, f, (size_t)N_EDGES + e);
        if (c < N_NODES && c / RANGE_SZ == X) {
            unsigned r = (unsigned)ldidx(ei, f, (size_t)e);
            if (r < N_NODES) {
                int p = offs[c] + atomicAdd(&fill[c], 1);
                srcs[p] = (int)r;
            }
        }
    }
}

// ---------- projection: g[i,:] = dis[i] * (h[i,:] @ W) ----------
// 4 waves split K; W quarter in VGPRs; row elements are wave-uniform -> s_load;
// inner loop is pure v_fma. Partials reduced via LDS every 16 rows.
template <int K>
__global__ __launch_bounds__(256) void k_proj(const float* __restrict__ in,
                                              const float* __restrict__ W,
                                              const float* __restrict__ dis,
                                              float* __restrict__ g) {
    const int KQ = K / 4;
    int wave = threadIdx.x >> 6;
    int lane = threadIdx.x & 63;
    float Wreg[KQ];
#pragma unroll
    for (int i = 0; i < KQ; i++) Wreg[i] = W[(wave * KQ + i) * 64 + lane];
    __shared__ float part[4][16][64];
    int base = blockIdx.x * 64;  // 64 rows per block
    for (int t = 0; t < 4; t++) {
        int r0 = base + t * 16;
        for (int r = 0; r < 16; r++) {
            int row = r0 + r;
            float acc = 0.f;
            if (row < N_NODES) {
                const float* xr = in + (size_t)row * K + wave * KQ;  // wave-uniform addr
#pragma unroll
                for (int i = 0; i < KQ; i++) acc = fmaf(xr[i], Wreg[i], acc);
            }
            part[wave][r][lane] = acc;
        }
        __syncthreads();
        for (int o = threadIdx.x; o < 16 * 64; o += 256) {
            int r = o >> 6, l = o & 63;
            int row = r0 + r;
            if (row < N_NODES) {
                float s = part[0][r][l] + part[1][r][l] + part[2][r][l] + part[3][r][l];
                g[(size_t)row * 64 + l] = dis[row] * s;
            }
        }
        __syncthreads();
    }
}

// ---------- CSR aggregation + finalize (4-way unrolled gather) ----------
template <bool RELU>
__global__ __launch_bounds__(256) void k_agg(const float* __restrict__ g,
                                             const int* __restrict__ srcs,
                                             const int* __restrict__ offs,
                                             const int* __restrict__ indeg,
                                             const float* __restrict__ dis,
                                             const float* __restrict__ b,
                                             float* __restrict__ out) {
    int node = (blockIdx.x * 256 + threadIdx.x) >> 6;
    int lane = threadIdx.x & 63;
    if (node >= N_NODES) return;
    int beg = offs[node];
    int deg = indeg[node];
    float a0 = g[(size_t)node * 64 + lane], a1 = 0.f, a2 = 0.f, a3 = 0.f;  // self loop
    int d = 0;
    while (d < deg) {
        int cnt = min(deg - d, 64);
        int sv = (lane < cnt) ? srcs[beg + d + lane] : 0;
        int j = 0;
        for (; j + 4 <= cnt; j += 4) {
            int s0 = __shfl(sv, j), s1 = __shfl(sv, j + 1);
            int s2 = __shfl(sv, j + 2), s3 = __shfl(sv, j + 3);
            a0 += g[(size_t)s0 * 64 + lane];
            a1 += g[(size_t)s1 * 64 + lane];
            a2 += g[(size_t)s2 * 64 + lane];
            a3 += g[(size_t)s3 * 64 + lane];
        }
        for (; j < cnt; j++) {
            int s = __shfl(sv, j);
            a0 += g[(size_t)s * 64 + lane];
        }
        d += cnt;
    }
    float v = dis[node] * (a0 + a1 + a2 + a3) + b[lane];
    if (RELU) v = fmaxf(v, 0.f);
    out[(size_t)node * 64 + lane] = v;
}

// ---------- pooling (batch sorted): per-graph sums + counts ----------
__global__ void k_pool(const float* h, const int* bat, const int* flag, float* sums, float* cnts) {
    const int R = 128;
    int wave = (blockIdx.x * 256 + threadIdx.x) >> 6;
    int lane = threadIdx.x & 63;
    int base = wave * R;
    if (base >= N_NODES) return;
    int f = *flag;
    int end = min(base + R, N_NODES);
    float acc = 0.f;
    int cur = ldidx(bat, f, (size_t)base);
    int cnt = 0;
    for (int r = base; r < end; r++) {
        int b = ldidx(bat, f, (size_t)r);
        if (b != cur) {
            if ((unsigned)cur < N_GRAPHS) {
                atomicAdd(&sums[cur * 64 + lane], acc);
                if (lane == 0) atomicAdd(&cnts[cur], (float)cnt);
            }
            acc = 0.f;
            cnt = 0;
            cur = b;
        }
        acc += h[(size_t)r * 64 + lane];
        cnt++;
    }
    if ((unsigned)cur < N_GRAPHS) {
        atomicAdd(&sums[cur * 64 + lane], acc);
        if (lane == 0) atomicAdd(&cnts[cur], (float)cnt);
    }
}

// ---------- head: out[g,o] = (sums[g,:]/cnt[g]) @ Wlin + blin (fp32 out) ----------
__global__ void k_head(const float* sums, const float* cnts, const float* Wlin,
                       const float* blin, float* out) {
    int t = blockIdx.x * 64 + threadIdx.x;
    if (t < N_GRAPHS * N_OUT) {
        int gph = t / N_OUT, o = t % N_OUT;
        float c = fmaxf(cnts[gph], 1.0f);
        float a = 0.f;
        for (int j = 0; j < HID; j++) a += sums[gph * 64 + j] * Wlin[j * N_OUT + o];
        out[t] = a / c + blin[o];
    }
}

extern "C" void kernel_launch(void* const* d_in, const int* in_sizes, int n_in,
                              void* d_out, int out_size, void* d_ws, size_t ws_size,
                              hipStream_t stream) {
    // --- resolve inputs by SIZE (robust to any harness input ordering) ---
    const float *x = nullptr, *W1 = nullptr, *W2 = nullptr, *W3 = nullptr, *Wlin = nullptr;
    const float *b1 = nullptr, *b2 = nullptr, *b3 = nullptr, *blin = nullptr;
    const int *ei = nullptr, *bat = nullptr;
    int n4096 = 0, n64 = 0;
    for (int i = 0; i < n_in; i++) {
        switch (in_sizes[i]) {
            case N_NODES * N_FEAT:  x    = (const float*)d_in[i]; break;
            case 2 * N_EDGES:       ei   = (const int*)d_in[i];   break;
            case N_NODES:           bat  = (const int*)d_in[i];   break;
            case N_FEAT * HID:      W1   = (const float*)d_in[i]; break;
            case HID * HID:
                if (n4096++ == 0) W2 = (const float*)d_in[i];
                else              W3 = (const float*)d_in[i];
                break;
            case HID * N_OUT:       Wlin = (const float*)d_in[i]; break;
            case HID:
                if (n64 == 0) b1 = (const float*)d_in[i];
                else if (n64 == 1) b2 = (const float*)d_in[i];
                else b3 = (const float*)d_in[i];
                n64++;
                break;
            case N_OUT:             blin = (const float*)d_in[i]; break;
            default: break;
        }
    }
    if (!x || !ei || !bat || !W1 || !W2 || !W3 || !Wlin || !b1 || !b2 || !b3 || !blin) {
        x    = (const float*)d_in[0];
        ei   = (const int*)d_in[1];
        bat  = (const int*)d_in[2];
        W1   = (const float*)d_in[3];  b1   = (const float*)d_in[4];
        W2   = (const float*)d_in[5];  b2   = (const float*)d_in[6];
        W3   = (const float*)d_in[7];  b3   = (const float*)d_in[8];
        Wlin = (const float*)d_in[9];  blin = (const float*)d_in[10];
    }
    float* out = (float*)d_out;  // fp32 output

    char* ws = (char*)d_ws;
    size_t off = 0;
    float* A     = (float*)(ws + off); off += (size_t)N_NODES * 64 * 4;
    float* B     = (float*)(ws + off); off += (size_t)N_NODES * 64 * 4;
    float* dis   = (float*)(ws + off); off += (size_t)N_NODES * 4;
    float* sums  = (float*)(ws + off); off += (size_t)N_GRAPHS * HID * 4;
    float* cnts  = (float*)(ws + off); off += (size_t)N_GRAPHS * 4;
    int*   indeg = (int*)(ws + off);   off += (size_t)N_NODES * 4;
    int*   incl  = (int*)(ws + off);   off += (size_t)N_NODES * 4;
    int*   offs  = (int*)(ws + off);   off += (size_t)N_NODES * 4;
    int*   fill  = (int*)(ws + off);   off += (size_t)N_NODES * 4;
    int*   bsum  = (int*)(ws + off);   off += 128 * 4;
    int*   srcs  = (int*)(ws + off);   off += (size_t)N_EDGES * 4;
    int*   flag  = (int*)(ws + off);   off += 4;

    const int nb_nodes = (N_NODES + 255) / 256;
    const int nb_proj  = (N_NODES + 63) / 64;       // 64 rows per block
    const int nb_agg   = (N_NODES * 64 + 255) / 256;
    const int nb_range = XRANGES * ECHUNKS;          // range-filtered edge kernels

    // --- index dtype detection ---
    k_detect<<<1, 256, 0, stream>>>(ei, flag);

    // --- CSR build (once, reused by all 3 convs) ---
    hipMemsetAsync(indeg, 0, (size_t)N_NODES * 4, stream);
    k_deg<<<nb_range, 256, 0, stream>>>(ei, flag, indeg);
    k_dis<<<nb_nodes, 256, 0, stream>>>(indeg, dis);
    k_scan1<<<NBLK, SCAN_B, 0, stream>>>(indeg, incl, bsum);
    k_scan2<<<1, 128, 0, stream>>>(bsum);
    k_scan3<<<NBLK, SCAN_B, 0, stream>>>(indeg, incl, bsum, offs, fill);
    k_place<<<nb_range, 256, 0, stream>>>(ei, flag, offs, fill, srcs);

    // conv1: x(fp32,128) -> B(g) -> A
    k_proj<128><<<nb_proj, 256, 0, stream>>>(x, W1, dis, B);
    k_agg<true><<<nb_agg, 256, 0, stream>>>(B, srcs, offs, indeg, dis, b1, A);

    // conv2: A -> B(g) -> A
    k_proj<64><<<nb_proj, 256, 0, stream>>>(A, W2, dis, B);
    k_agg<true><<<nb_agg, 256, 0, stream>>>(B, srcs, offs, indeg, dis, b2, A);

    // conv3: A -> B(g) -> A (no relu)
    k_proj<64><<<nb_proj, 256, 0, stream>>>(A, W3, dis, B);
    k_agg<false><<<nb_agg, 256, 0, stream>>>(B, srcs, offs, indeg, dis, b3, A);

    // pool + head
    hipMemsetAsync(sums, 0, (size_t)(N_GRAPHS * HID + N_GRAPHS) * 4, stream);
    const int nwaves = (N_NODES + 127) / 128;
    k_pool<<<(nwaves * 64 + 255) / 256, 256, 0, stream>>>(A, bat, flag, sums, cnts);
    k_head<<<(N_GRAPHS * N_OUT + 63) / 64, 64, 0, stream>>>(sums, cnts, Wlin, blin, out);
}

// Round 8
// 525.714 us; speedup vs baseline: 8.7224x; 1.3865x over previous
//
#include <hip/hip_runtime.h>
#include <hip/hip_bf16.h>

#define N_NODES 100000
#define N_EDGES 1600000
#define N_FEAT 128
#define HID 64
#define N_GRAPHS 64
#define N_OUT 10
#define SCAN_B 1024
#define NBLK ((N_NODES + SCAN_B - 1) / SCAN_B)  // 98
#define XRANGES 8
#define RANGE_SZ ((N_NODES + XRANGES - 1) / XRANGES)  // 12500
#define ECHUNKS ((N_EDGES + 255) / 256)  // 6250

typedef __attribute__((ext_vector_type(8))) short bf8_t;   // 8 bf16 in 4 VGPRs
typedef __attribute__((ext_vector_type(4))) float f4_t;    // MFMA accumulator

__device__ __forceinline__ short f2bf(float f) {
    __hip_bfloat16 h = __float2bfloat16(f);
    return *(short*)&h;
}

// ---------- index dtype probe: 1 = int64 storage, 0 = int32 storage ----------
__global__ void k_detect(const int* raw, int* flag) {
    __shared__ int any;
    if (threadIdx.x == 0) any = 0;
    __syncthreads();
    int v = raw[2 * threadIdx.x + 1] | raw[2 * (threadIdx.x + 256) + 1] |
            raw[2 * (threadIdx.x + 512) + 1] | raw[2 * (threadIdx.x + 768) + 1];
    if (v != 0) any = 1;  // benign race
    __syncthreads();
    if (threadIdx.x == 0) *flag = (any == 0) ? 1 : 0;
}

__device__ __forceinline__ int ldidx(const int* raw, int f, size_t i) {
    return f ? raw[2 * i] : raw[i];
}

// ---------- in-degree, XCD-range filtered ----------
__global__ void k_deg(const int* ei, const int* flag, int* indeg) {
    unsigned X = blockIdx.x & (XRANGES - 1);
    int e = (blockIdx.x >> 3) * 256 + threadIdx.x;
    if (e < N_EDGES) {
        int f = *flag;
        unsigned c = (unsigned)ldidx(ei, f, (size_t)N_EDGES + e);
        if (c < N_NODES && c / RANGE_SZ == X) atomicAdd(&indeg[c], 1);
    }
}

__global__ void k_dis(const int* indeg, float* dis) {
    int i = blockIdx.x * 256 + threadIdx.x;
    if (i < N_NODES) dis[i] = rsqrtf((float)indeg[i] + 1.0f);
}

// ---------- 3-kernel exclusive prefix scan of indeg -> offs ----------
__global__ __launch_bounds__(SCAN_B) void k_scan1(const int* indeg, int* incl, int* bsum) {
    __shared__ int tmp[SCAN_B];
    int i = blockIdx.x * SCAN_B + threadIdx.x;
    tmp[threadIdx.x] = (i < N_NODES) ? indeg[i] : 0;
    __syncthreads();
    for (int d = 1; d < SCAN_B; d <<= 1) {
        int t = (threadIdx.x >= d) ? tmp[threadIdx.x - d] : 0;
        __syncthreads();
        tmp[threadIdx.x] += t;
        __syncthreads();
    }
    if (i < N_NODES) incl[i] = tmp[threadIdx.x];
    if (threadIdx.x == SCAN_B - 1) bsum[blockIdx.x] = tmp[threadIdx.x];
}

__global__ void k_scan2(int* bsum) {
    __shared__ int tmp[128];
    tmp[threadIdx.x] = (threadIdx.x < NBLK) ? bsum[threadIdx.x] : 0;
    __syncthreads();
    for (int d = 1; d < 128; d <<= 1) {
        int t = (threadIdx.x >= d) ? tmp[threadIdx.x - d] : 0;
        __syncthreads();
        tmp[threadIdx.x] += t;
        __syncthreads();
    }
    if (threadIdx.x < NBLK) bsum[threadIdx.x] = tmp[threadIdx.x];
}

__global__ __launch_bounds__(SCAN_B) void k_scan3(const int* indeg, const int* incl,
                                                  const int* bsum, int* offs, int* fill) {
    int i = blockIdx.x * SCAN_B + threadIdx.x;
    if (i < N_NODES) {
        int pre = (blockIdx.x > 0) ? bsum[blockIdx.x - 1] : 0;
        offs[i] = incl[i] - indeg[i] + pre;
        fill[i] = 0;
    }
}

// ---------- CSR placement, XCD-range filtered ----------
__global__ void k_place(const int* ei, const int* flag, const int* offs, int* fill, int* srcs) {
    unsigned X = blockIdx.x & (XRANGES - 1);
    int e = (blockIdx.x >> 3) * 256 + threadIdx.x;
    if (e < N_EDGES) {
        int f = *flag;
        unsigned c = (unsigned)ldidx(ei, f, (size_t)N_EDGES + e);
        if (c < N_NODES && c / RANGE_SZ == X) {
            unsigned r = (unsigned)ldidx(ei, f, (size_t)e);
            if (r < N_NODES) {
                int p = offs[c] + atomicAdd(&fill[c], 1);
                srcs[p] = (int)r;
            }
        }
    }
}

// ---------- projection via MFMA: g[i,:] = dis[i] * (x[i,:] @ W) ----------
// fp32 in/out; bf16 MFMA internally (fp32 accumulate). Per wave: 16-row chunk,
// 64 output cols = 4 col-tiles of 16x16x32 MFMA; W frags resident in VGPRs.
// Layouts (guide-verified): A[m=lane&15][k=quad*8+j]; B[k=quad*8+j][n=lane&15];
// C/D: col=lane&15, row=quad*4+reg. N_NODES = 6250*16 exactly -> no ragged tail.
template <int K>
__global__ __launch_bounds__(256) void k_proj(const float* __restrict__ in,
                                              const float* __restrict__ W,
                                              const float* __restrict__ dis,
                                              float* __restrict__ g) {
    const int NS = K / 32;
    int wave = threadIdx.x >> 6, lane = threadIdx.x & 63;
    int m = lane & 15, quad = lane >> 4;
    bf8_t Bf[NS][4];
#pragma unroll
    for (int s = 0; s < NS; s++)
#pragma unroll
        for (int t = 0; t < 4; t++)
#pragma unroll
            for (int j = 0; j < 8; j++)
                Bf[s][t][j] = f2bf(W[(s * 32 + quad * 8 + j) * 64 + t * 16 + m]);

    const int nchunks = N_NODES / 16;  // 6250
    const int stride = gridDim.x * 4;
    for (int chunk = blockIdx.x * 4 + wave; chunk < nchunks; chunk += stride) {
        int r0 = chunk * 16;
        const float* src = in + (size_t)(r0 + m) * K + quad * 8;
        f4_t acc[4] = {{0.f, 0.f, 0.f, 0.f}, {0.f, 0.f, 0.f, 0.f},
                       {0.f, 0.f, 0.f, 0.f}, {0.f, 0.f, 0.f, 0.f}};
#pragma unroll
        for (int s = 0; s < NS; s++) {
            bf8_t a;
#pragma unroll
            for (int j = 0; j < 8; j++) a[j] = f2bf(src[s * 32 + j]);
#pragma unroll
            for (int t = 0; t < 4; t++)
                acc[t] = __builtin_amdgcn_mfma_f32_16x16x32_bf16(a, Bf[s][t], acc[t], 0, 0, 0);
        }
        float dv[4];
#pragma unroll
        for (int i = 0; i < 4; i++) dv[i] = dis[r0 + quad * 4 + i];
#pragma unroll
        for (int t = 0; t < 4; t++)
#pragma unroll
            for (int i = 0; i < 4; i++)
                g[(size_t)(r0 + quad * 4 + i) * 64 + t * 16 + m] = dv[i] * acc[t][i];
    }
}

// ---------- CSR aggregation + finalize (4-way unrolled gather) ----------
template <bool RELU>
__global__ __launch_bounds__(256) void k_agg(const float* __restrict__ g,
                                             const int* __restrict__ srcs,
                                             const int* __restrict__ offs,
                                             const int* __restrict__ indeg,
                                             const float* __restrict__ dis,
                                             const float* __restrict__ b,
                                             float* __restrict__ out) {
    int node = (blockIdx.x * 256 + threadIdx.x) >> 6;
    int lane = threadIdx.x & 63;
    if (node >= N_NODES) return;
    int beg = offs[node];
    int deg = indeg[node];
    float a0 = g[(size_t)node * 64 + lane], a1 = 0.f, a2 = 0.f, a3 = 0.f;  // self loop
    int d = 0;
    while (d < deg) {
        int cnt = min(deg - d, 64);
        int sv = (lane < cnt) ? srcs[beg + d + lane] : 0;
        int j = 0;
        for (; j + 4 <= cnt; j += 4) {
            int s0 = __shfl(sv, j), s1 = __shfl(sv, j + 1);
            int s2 = __shfl(sv, j + 2), s3 = __shfl(sv, j + 3);
            a0 += g[(size_t)s0 * 64 + lane];
            a1 += g[(size_t)s1 * 64 + lane];
            a2 += g[(size_t)s2 * 64 + lane];
            a3 += g[(size_t)s3 * 64 + lane];
        }
        for (; j < cnt; j++) {
            int s = __shfl(sv, j);
            a0 += g[(size_t)s * 64 + lane];
        }
        d += cnt;
    }
    float v = dis[node] * (a0 + a1 + a2 + a3) + b[lane];
    if (RELU) v = fmaxf(v, 0.f);
    out[(size_t)node * 64 + lane] = v;
}

// ---------- pooling (batch sorted): per-graph sums + counts ----------
__global__ void k_pool(const float* h, const int* bat, const int* flag, float* sums, float* cnts) {
    const int R = 128;
    int wave = (blockIdx.x * 256 + threadIdx.x) >> 6;
    int lane = threadIdx.x & 63;
    int base = wave * R;
    if (base >= N_NODES) return;
    int f = *flag;
    int end = min(base + R, N_NODES);
    float acc = 0.f;
    int cur = ldidx(bat, f, (size_t)base);
    int cnt = 0;
    for (int r = base; r < end; r++) {
        int b = ldidx(bat, f, (size_t)r);
        if (b != cur) {
            if ((unsigned)cur < N_GRAPHS) {
                atomicAdd(&sums[cur * 64 + lane], acc);
                if (lane == 0) atomicAdd(&cnts[cur], (float)cnt);
            }
            acc = 0.f;
            cnt = 0;
            cur = b;
        }
        acc += h[(size_t)r * 64 + lane];
        cnt++;
    }
    if ((unsigned)cur < N_GRAPHS) {
        atomicAdd(&sums[cur * 64 + lane], acc);
        if (lane == 0) atomicAdd(&cnts[cur], (float)cnt);
    }
}

// ---------- head: out[g,o] = (sums[g,:]/cnt[g]) @ Wlin + blin (fp32 out) ----------
__global__ void k_head(const float* sums, const float* cnts, const float* Wlin,
                       const float* blin, float* out) {
    int t = blockIdx.x * 64 + threadIdx.x;
    if (t < N_GRAPHS * N_OUT) {
        int gph = t / N_OUT, o = t % N_OUT;
        float c = fmaxf(cnts[gph], 1.0f);
        float a = 0.f;
        for (int j = 0; j < HID; j++) a += sums[gph * 64 + j] * Wlin[j * N_OUT + o];
        out[t] = a / c + blin[o];
    }
}

extern "C" void kernel_launch(void* const* d_in, const int* in_sizes, int n_in,
                              void* d_out, int out_size, void* d_ws, size_t ws_size,
                              hipStream_t stream) {
    // --- resolve inputs by SIZE (robust to any harness input ordering) ---
    const float *x = nullptr, *W1 = nullptr, *W2 = nullptr, *W3 = nullptr, *Wlin = nullptr;
    const float *b1 = nullptr, *b2 = nullptr, *b3 = nullptr, *blin = nullptr;
    const int *ei = nullptr, *bat = nullptr;
    int n4096 = 0, n64 = 0;
    for (int i = 0; i < n_in; i++) {
        switch (in_sizes[i]) {
            case N_NODES * N_FEAT:  x    = (const float*)d_in[i]; break;
            case 2 * N_EDGES:       ei   = (const int*)d_in[i];   break;
            case N_NODES:           bat  = (const int*)d_in[i];   break;
            case N_FEAT * HID:      W1   = (const float*)d_in[i]; break;
            case HID * HID:
                if (n4096++ == 0) W2 = (const float*)d_in[i];
                else              W3 = (const float*)d_in[i];
                break;
            case HID * N_OUT:       Wlin = (const float*)d_in[i]; break;
            case HID:
                if (n64 == 0) b1 = (const float*)d_in[i];
                else if (n64 == 1) b2 = (const float*)d_in[i];
                else b3 = (const float*)d_in[i];
                n64++;
                break;
            case N_OUT:             blin = (const float*)d_in[i]; break;
            default: break;
        }
    }
    if (!x || !ei || !bat || !W1 || !W2 || !W3 || !Wlin || !b1 || !b2 || !b3 || !blin) {
        x    = (const float*)d_in[0];
        ei   = (const int*)d_in[1];
        bat  = (const int*)d_in[2];
        W1   = (const float*)d_in[3];  b1   = (const float*)d_in[4];
        W2   = (const float*)d_in[5];  b2   = (const float*)d_in[6];
        W3   = (const float*)d_in[7];  b3   = (const float*)d_in[8];
        Wlin = (const float*)d_in[9];  blin = (const float*)d_in[10];
    }
    float* out = (float*)d_out;  // fp32 output

    char* ws = (char*)d_ws;
    size_t off = 0;
    float* A     = (float*)(ws + off); off += (size_t)N_NODES * 64 * 4;
    float* B     = (float*)(ws + off); off += (size_t)N_NODES * 64 * 4;
    float* dis   = (float*)(ws + off); off += (size_t)N_NODES * 4;
    float* sums  = (float*)(ws + off); off += (size_t)N_GRAPHS * HID * 4;
    float* cnts  = (float*)(ws + off); off += (size_t)N_GRAPHS * 4;
    int*   indeg = (int*)(ws + off);   off += (size_t)N_NODES * 4;
    int*   incl  = (int*)(ws + off);   off += (size_t)N_NODES * 4;
    int*   offs  = (int*)(ws + off);   off += (size_t)N_NODES * 4;
    int*   fill  = (int*)(ws + off);   off += (size_t)N_NODES * 4;
    int*   bsum  = (int*)(ws + off);   off += 128 * 4;
    int*   srcs  = (int*)(ws + off);   off += (size_t)N_EDGES * 4;
    int*   flag  = (int*)(ws + off);   off += 4;

    const int nb_nodes = (N_NODES + 255) / 256;
    const int nb_agg   = (N_NODES * 64 + 255) / 256;
    const int nb_range = XRANGES * ECHUNKS;

    // --- index dtype detection ---
    k_detect<<<1, 256, 0, stream>>>(ei, flag);

    // --- CSR build (once, reused by all 3 convs) ---
    hipMemsetAsync(indeg, 0, (size_t)N_NODES * 4, stream);
    k_deg<<<nb_range, 256, 0, stream>>>(ei, flag, indeg);
    k_dis<<<nb_nodes, 256, 0, stream>>>(indeg, dis);
    k_scan1<<<NBLK, SCAN_B, 0, stream>>>(indeg, incl, bsum);
    k_scan2<<<1, 128, 0, stream>>>(bsum);
    k_scan3<<<NBLK, SCAN_B, 0, stream>>>(indeg, incl, bsum, offs, fill);
    k_place<<<nb_range, 256, 0, stream>>>(ei, flag, offs, fill, srcs);

    // conv1: x(fp32,128) -> B(g) -> A
    k_proj<128><<<512, 256, 0, stream>>>(x, W1, dis, B);
    k_agg<true><<<nb_agg, 256, 0, stream>>>(B, srcs, offs, indeg, dis, b1, A);

    // conv2: A -> B(g) -> A
    k_proj<64><<<512, 256, 0, stream>>>(A, W2, dis, B);
    k_agg<true><<<nb_agg, 256, 0, stream>>>(B, srcs, offs, indeg, dis, b2, A);

    // conv3: A -> B(g) -> A (no relu)
    k_proj<64><<<512, 256, 0, stream>>>(A, W3, dis, B);
    k_agg<false><<<nb_agg, 256, 0, stream>>>(B, srcs, offs, indeg, dis, b3, A);

    // pool + head
    hipMemsetAsync(sums, 0, (size_t)(N_GRAPHS * HID + N_GRAPHS) * 4, stream);
    const int nwaves = (N_NODES + 127) / 128;
    k_pool<<<(nwaves * 64 + 255) / 256, 256, 0, stream>>>(A, bat, flag, sums, cnts);
    k_head<<<(N_GRAPHS * N_OUT + 63) / 64, 64, 0, stream>>>(sums, cnts, Wlin, blin, out);
}

// Round 9
// 488.244 us; speedup vs baseline: 9.3918x; 1.0767x over previous
//
#include <hip/hip_runtime.h>
#include <hip/hip_bf16.h>

#define N_NODES 100000
#define N_EDGES 1600000
#define N_FEAT 128
#define HID 64
#define N_GRAPHS 64
#define N_OUT 10
#define SCAN_B 1024
#define NBLK ((N_NODES + SCAN_B - 1) / SCAN_B)  // 98
#define XRANGES 8
#define RANGE_SZ ((N_NODES + XRANGES - 1) / XRANGES)  // 12500
#define ECHUNKS ((N_EDGES + 255) / 256)  // 6250

typedef __attribute__((ext_vector_type(8))) short bf8_t;   // 8 bf16 in 4 VGPRs
typedef __attribute__((ext_vector_type(4))) float f4_t;    // MFMA accumulator

__device__ __forceinline__ short f2bf(float f) {
    __hip_bfloat16 h = __float2bfloat16(f);
    return *(short*)&h;
}
__device__ __forceinline__ float bf2f(unsigned short u) {
    unsigned v = ((unsigned)u) << 16;
    return __builtin_bit_cast(float, v);
}

// ---------- index dtype probe: 1 = int64 storage, 0 = int32 storage ----------
__global__ void k_detect(const int* raw, int* flag) {
    __shared__ int any;
    if (threadIdx.x == 0) any = 0;
    __syncthreads();
    int v = raw[2 * threadIdx.x + 1] | raw[2 * (threadIdx.x + 256) + 1] |
            raw[2 * (threadIdx.x + 512) + 1] | raw[2 * (threadIdx.x + 768) + 1];
    if (v != 0) any = 1;  // benign race
    __syncthreads();
    if (threadIdx.x == 0) *flag = (any == 0) ? 1 : 0;
}

__device__ __forceinline__ int ldidx(const int* raw, int f, size_t i) {
    return f ? raw[2 * i] : raw[i];
}

// ---------- in-degree (single pass; atomic payload tiny, filter not worth 8x reads) ----------
__global__ void k_deg(const int* ei, const int* flag, int* indeg) {
    int e = blockIdx.x * 256 + threadIdx.x;
    if (e < N_EDGES) {
        int f = *flag;
        unsigned c = (unsigned)ldidx(ei, f, (size_t)N_EDGES + e);
        if (c < N_NODES) atomicAdd(&indeg[c], 1);
    }
}

__global__ void k_dis(const int* indeg, float* dis) {
    int i = blockIdx.x * 256 + threadIdx.x;
    if (i < N_NODES) dis[i] = rsqrtf((float)indeg[i] + 1.0f);
}

// ---------- 3-kernel exclusive prefix scan of indeg -> offs ----------
__global__ __launch_bounds__(SCAN_B) void k_scan1(const int* indeg, int* incl, int* bsum) {
    __shared__ int tmp[SCAN_B];
    int i = blockIdx.x * SCAN_B + threadIdx.x;
    tmp[threadIdx.x] = (i < N_NODES) ? indeg[i] : 0;
    __syncthreads();
    for (int d = 1; d < SCAN_B; d <<= 1) {
        int t = (threadIdx.x >= d) ? tmp[threadIdx.x - d] : 0;
        __syncthreads();
        tmp[threadIdx.x] += t;
        __syncthreads();
    }
    if (i < N_NODES) incl[i] = tmp[threadIdx.x];
    if (threadIdx.x == SCAN_B - 1) bsum[blockIdx.x] = tmp[threadIdx.x];
}

__global__ void k_scan2(int* bsum) {
    __shared__ int tmp[128];
    tmp[threadIdx.x] = (threadIdx.x < NBLK) ? bsum[threadIdx.x] : 0;
    __syncthreads();
    for (int d = 1; d < 128; d <<= 1) {
        int t = (threadIdx.x >= d) ? tmp[threadIdx.x - d] : 0;
        __syncthreads();
        tmp[threadIdx.x] += t;
        __syncthreads();
    }
    if (threadIdx.x < NBLK) bsum[threadIdx.x] = tmp[threadIdx.x];
}

__global__ __launch_bounds__(SCAN_B) void k_scan3(const int* indeg, const int* incl,
                                                  const int* bsum, int* offs, int* fill) {
    int i = blockIdx.x * SCAN_B + threadIdx.x;
    if (i < N_NODES) {
        int pre = (blockIdx.x > 0) ? bsum[blockIdx.x - 1] : 0;
        offs[i] = incl[i] - indeg[i] + pre;
        fill[i] = 0;
    }
}

// ---------- CSR placement, XCD-range filtered ----------
__global__ void k_place(const int* ei, const int* flag, const int* offs, int* fill, int* srcs) {
    unsigned X = blockIdx.x & (XRANGES - 1);
    int e = (blockIdx.x >> 3) * 256 + threadIdx.x;
    if (e < N_EDGES) {
        int f = *flag;
        unsigned c = (unsigned)ldidx(ei, f, (size_t)N_EDGES + e);
        if (c < N_NODES && c / RANGE_SZ == X) {
            unsigned r = (unsigned)ldidx(ei, f, (size_t)e);
            if (r < N_NODES) {
                int p = offs[c] + atomicAdd(&fill[c], 1);
                srcs[p] = (int)r;
            }
        }
    }
}

// ---------- projection via MFMA: g[i,:] = bf16( dis[i] * (x[i,:] @ W) ) ----------
// fp32 in; bf16 MFMA internally (fp32 accumulate); bf16 out (halves agg gather traffic).
template <int K>
__global__ __launch_bounds__(256) void k_proj(const float* __restrict__ in,
                                              const float* __restrict__ W,
                                              const float* __restrict__ dis,
                                              unsigned short* __restrict__ g) {
    const int NS = K / 32;
    int wave = threadIdx.x >> 6, lane = threadIdx.x & 63;
    int m = lane & 15, quad = lane >> 4;
    bf8_t Bf[NS][4];
#pragma unroll
    for (int s = 0; s < NS; s++)
#pragma unroll
        for (int t = 0; t < 4; t++)
#pragma unroll
            for (int j = 0; j < 8; j++)
                Bf[s][t][j] = f2bf(W[(s * 32 + quad * 8 + j) * 64 + t * 16 + m]);

    const int nchunks = N_NODES / 16;  // 6250
    const int stride = gridDim.x * 4;
    for (int chunk = blockIdx.x * 4 + wave; chunk < nchunks; chunk += stride) {
        int r0 = chunk * 16;
        const float* src = in + (size_t)(r0 + m) * K + quad * 8;
        f4_t acc[4] = {{0.f, 0.f, 0.f, 0.f}, {0.f, 0.f, 0.f, 0.f},
                       {0.f, 0.f, 0.f, 0.f}, {0.f, 0.f, 0.f, 0.f}};
#pragma unroll
        for (int s = 0; s < NS; s++) {
            bf8_t a;
#pragma unroll
            for (int j = 0; j < 8; j++) a[j] = f2bf(src[s * 32 + j]);
#pragma unroll
            for (int t = 0; t < 4; t++)
                acc[t] = __builtin_amdgcn_mfma_f32_16x16x32_bf16(a, Bf[s][t], acc[t], 0, 0, 0);
        }
        float dv[4];
#pragma unroll
        for (int i = 0; i < 4; i++) dv[i] = dis[r0 + quad * 4 + i];
#pragma unroll
        for (int t = 0; t < 4; t++)
#pragma unroll
            for (int i = 0; i < 4; i++)
                g[(size_t)(r0 + quad * 4 + i) * 64 + t * 16 + m] =
                    (unsigned short)f2bf(dv[i] * acc[t][i]);
    }
}

// ---------- CSR aggregation + finalize (bf16 gathers, fp32 accumulate) ----------
template <bool RELU>
__global__ __launch_bounds__(256) void k_agg(const unsigned short* __restrict__ g,
                                             const int* __restrict__ srcs,
                                             const int* __restrict__ offs,
                                             const int* __restrict__ indeg,
                                             const float* __restrict__ dis,
                                             const float* __restrict__ b,
                                             float* __restrict__ out) {
    int node = (blockIdx.x * 256 + threadIdx.x) >> 6;
    int lane = threadIdx.x & 63;
    if (node >= N_NODES) return;
    int beg = offs[node];
    int deg = indeg[node];
    float a0 = bf2f(g[(size_t)node * 64 + lane]), a1 = 0.f, a2 = 0.f, a3 = 0.f;  // self loop
    int d = 0;
    while (d < deg) {
        int cnt = min(deg - d, 64);
        int sv = (lane < cnt) ? srcs[beg + d + lane] : 0;
        int j = 0;
        for (; j + 4 <= cnt; j += 4) {
            int s0 = __shfl(sv, j), s1 = __shfl(sv, j + 1);
            int s2 = __shfl(sv, j + 2), s3 = __shfl(sv, j + 3);
            a0 += bf2f(g[(size_t)s0 * 64 + lane]);
            a1 += bf2f(g[(size_t)s1 * 64 + lane]);
            a2 += bf2f(g[(size_t)s2 * 64 + lane]);
            a3 += bf2f(g[(size_t)s3 * 64 + lane]);
        }
        for (; j < cnt; j++) {
            int s = __shfl(sv, j);
            a0 += bf2f(g[(size_t)s * 64 + lane]);
        }
        d += cnt;
    }
    float v = dis[node] * (a0 + a1 + a2 + a3) + b[lane];
    if (RELU) v = fmaxf(v, 0.f);
    out[(size_t)node * 64 + lane] = v;
}

// ---------- pooling (batch sorted): per-graph sums + counts ----------
__global__ void k_pool(const float* h, const int* bat, const int* flag, float* sums, float* cnts) {
    const int R = 128;
    int wave = (blockIdx.x * 256 + threadIdx.x) >> 6;
    int lane = threadIdx.x & 63;
    int base = wave * R;
    if (base >= N_NODES) return;
    int f = *flag;
    int end = min(base + R, N_NODES);
    float acc = 0.f;
    int cur = ldidx(bat, f, (size_t)base);
    int cnt = 0;
    for (int r = base; r < end; r++) {
        int b = ldidx(bat, f, (size_t)r);
        if (b != cur) {
            if ((unsigned)cur < N_GRAPHS) {
                atomicAdd(&sums[cur * 64 + lane], acc);
                if (lane == 0) atomicAdd(&cnts[cur], (float)cnt);
            }
            acc = 0.f;
            cnt = 0;
            cur = b;
        }
        acc += h[(size_t)r * 64 + lane];
        cnt++;
    }
    if ((unsigned)cur < N_GRAPHS) {
        atomicAdd(&sums[cur * 64 + lane], acc);
        if (lane == 0) atomicAdd(&cnts[cur], (float)cnt);
    }
}

// ---------- head: out[g,o] = (sums[g,:]/cnt[g]) @ Wlin + blin (fp32 out) ----------
__global__ void k_head(const float* sums, const float* cnts, const float* Wlin,
                       const float* blin, float* out) {
    int t = blockIdx.x * 64 + threadIdx.x;
    if (t < N_GRAPHS * N_OUT) {
        int gph = t / N_OUT, o = t % N_OUT;
        float c = fmaxf(cnts[gph], 1.0f);
        float a = 0.f;
        for (int j = 0; j < HID; j++) a += sums[gph * 64 + j] * Wlin[j * N_OUT + o];
        out[t] = a / c + blin[o];
    }
}

extern "C" void kernel_launch(void* const* d_in, const int* in_sizes, int n_in,
                              void* d_out, int out_size, void* d_ws, size_t ws_size,
                              hipStream_t stream) {
    // --- resolve inputs by SIZE (robust to any harness input ordering) ---
    const float *x = nullptr, *W1 = nullptr, *W2 = nullptr, *W3 = nullptr, *Wlin = nullptr;
    const float *b1 = nullptr, *b2 = nullptr, *b3 = nullptr, *blin = nullptr;
    const int *ei = nullptr, *bat = nullptr;
    int n4096 = 0, n64 = 0;
    for (int i = 0; i < n_in; i++) {
        switch (in_sizes[i]) {
            case N_NODES * N_FEAT:  x    = (const float*)d_in[i]; break;
            case 2 * N_EDGES:       ei   = (const int*)d_in[i];   break;
            case N_NODES:           bat  = (const int*)d_in[i];   break;
            case N_FEAT * HID:      W1   = (const float*)d_in[i]; break;
            case HID * HID:
                if (n4096++ == 0) W2 = (const float*)d_in[i];
                else              W3 = (const float*)d_in[i];
                break;
            case HID * N_OUT:       Wlin = (const float*)d_in[i]; break;
            case HID:
                if (n64 == 0) b1 = (const float*)d_in[i];
                else if (n64 == 1) b2 = (const float*)d_in[i];
                else b3 = (const float*)d_in[i];
                n64++;
                break;
            case N_OUT:             blin = (const float*)d_in[i]; break;
            default: break;
        }
    }
    if (!x || !ei || !bat || !W1 || !W2 || !W3 || !Wlin || !b1 || !b2 || !b3 || !blin) {
        x    = (const float*)d_in[0];
        ei   = (const int*)d_in[1];
        bat  = (const int*)d_in[2];
        W1   = (const float*)d_in[3];  b1   = (const float*)d_in[4];
        W2   = (const float*)d_in[5];  b2   = (const float*)d_in[6];
        W3   = (const float*)d_in[7];  b3   = (const float*)d_in[8];
        Wlin = (const float*)d_in[9];  blin = (const float*)d_in[10];
    }
    float* out = (float*)d_out;  // fp32 output

    char* ws = (char*)d_ws;
    size_t off = 0;
    float*          A     = (float*)(ws + off);          off += (size_t)N_NODES * 64 * 4;
    unsigned short* G     = (unsigned short*)(ws + off); off += (size_t)N_NODES * 64 * 2;
    float*          dis   = (float*)(ws + off);          off += (size_t)N_NODES * 4;
    float*          sums  = (float*)(ws + off);          off += (size_t)N_GRAPHS * HID * 4;
    float*          cnts  = (float*)(ws + off);          off += (size_t)N_GRAPHS * 4;
    int*            indeg = (int*)(ws + off);            off += (size_t)N_NODES * 4;
    int*            incl  = (int*)(ws + off);            off += (size_t)N_NODES * 4;
    int*            offs  = (int*)(ws + off);            off += (size_t)N_NODES * 4;
    int*            fill  = (int*)(ws + off);            off += (size_t)N_NODES * 4;
    int*            bsum  = (int*)(ws + off);            off += 128 * 4;
    int*            srcs  = (int*)(ws + off);            off += (size_t)N_EDGES * 4;
    int*            flag  = (int*)(ws + off);            off += 4;

    const int nb_nodes = (N_NODES + 255) / 256;
    const int nb_edges = (N_EDGES + 255) / 256;
    const int nb_agg   = (N_NODES * 64 + 255) / 256;
    const int nb_range = XRANGES * ECHUNKS;

    // --- index dtype detection ---
    k_detect<<<1, 256, 0, stream>>>(ei, flag);

    // --- CSR build (once, reused by all 3 convs) ---
    hipMemsetAsync(indeg, 0, (size_t)N_NODES * 4, stream);
    k_deg<<<nb_edges, 256, 0, stream>>>(ei, flag, indeg);
    k_dis<<<nb_nodes, 256, 0, stream>>>(indeg, dis);
    k_scan1<<<NBLK, SCAN_B, 0, stream>>>(indeg, incl, bsum);
    k_scan2<<<1, 128, 0, stream>>>(bsum);
    k_scan3<<<NBLK, SCAN_B, 0, stream>>>(indeg, incl, bsum, offs, fill);
    k_place<<<nb_range, 256, 0, stream>>>(ei, flag, offs, fill, srcs);

    // conv1: x(fp32,128) -> G(bf16) -> A
    k_proj<128><<<512, 256, 0, stream>>>(x, W1, dis, G);
    k_agg<true><<<nb_agg, 256, 0, stream>>>(G, srcs, offs, indeg, dis, b1, A);

    // conv2: A -> G -> A
    k_proj<64><<<512, 256, 0, stream>>>(A, W2, dis, G);
    k_agg<true><<<nb_agg, 256, 0, stream>>>(G, srcs, offs, indeg, dis, b2, A);

    // conv3: A -> G -> A (no relu)
    k_proj<64><<<512, 256, 0, stream>>>(A, W3, dis, G);
    k_agg<false><<<nb_agg, 256, 0, stream>>>(G, srcs, offs, indeg, dis, b3, A);

    // pool + head
    hipMemsetAsync(sums, 0, (size_t)(N_GRAPHS * HID + N_GRAPHS) * 4, stream);
    const int nwaves = (N_NODES + 127) / 128;
    k_pool<<<(nwaves * 64 + 255) / 256, 256, 0, stream>>>(A, bat, flag, sums, cnts);
    k_head<<<(N_GRAPHS * N_OUT + 63) / 64, 64, 0, stream>>>(sums, cnts, Wlin, blin, out);
}